// Round 1
// baseline (622.085 us; speedup 1.0000x reference)
//
#include <hip/hip_runtime.h>
#include <hip/hip_bf16.h>
#include <stdint.h>

// LDPC BayesianOddLayer.
// Structure: sparse extraction of Tanner-graph masks (done on-device every
// launch since masks arrive as dense inputs), then a fused SpMM + skip-gather
// + 5-member threefry-dropout/tanh ensemble.
//
// TF_PARTITIONABLE=1 -> jax_threefry_partitionable semantics (default True in
// JAX >= 0.4.36): split = fold_in(iota), bits32 = o0^o1 of tf(key; hi,lo).
// TF_PARTITIONABLE=0 -> legacy: split via iota(2n) halves, bits via iota(n)
// halves. Flip if absmax ~O(0.4).
#define TF_PARTITIONABLE 1

#define NEDGE 4096
#define NVAR  1024
#define NBATCH 4096
#define CAP   32      // max nnz per odd-mask column (deg(v)-1, Poisson(4) tail)
#define BROWS 8       // batch rows per thread in main kernel
#define NTOTAL (NBATCH * NEDGE)   // 16,777,216
#define NHALF  (NTOTAL / 2)

__device__ __forceinline__ uint32_t rotl32(uint32_t x, int d) {
  return (x << d) | (x >> (32 - d));
}

// JAX threefry2x32, 20 rounds.
__device__ __forceinline__ void tf2x32(uint32_t k0, uint32_t k1,
                                       uint32_t x0, uint32_t x1,
                                       uint32_t& o0, uint32_t& o1) {
  const uint32_t ks2 = k0 ^ k1 ^ 0x1BD11BDAu;
  x0 += k0; x1 += k1;
#define TF_R(r) { x0 += x1; x1 = rotl32(x1, r); x1 ^= x0; }
  TF_R(13) TF_R(15) TF_R(26) TF_R(6)   x0 += k1;  x1 += ks2 + 1u;
  TF_R(17) TF_R(29) TF_R(16) TF_R(24)  x0 += ks2; x1 += k0 + 2u;
  TF_R(13) TF_R(15) TF_R(26) TF_R(6)   x0 += k0;  x1 += k1 + 3u;
  TF_R(17) TF_R(29) TF_R(16) TF_R(24)  x0 += k1;  x1 += ks2 + 4u;
  TF_R(13) TF_R(15) TF_R(26) TF_R(6)   x0 += ks2; x1 += k0 + 5u;
#undef TF_R
  o0 = x0; o1 = x1;
}

// Kernel 0: zero per-column counters; thread 0 derives the 5 ensemble subkeys
// from jax.random.split(jax.random.key(42), 5).
__global__ void prep_zero_keys(uint32_t* __restrict__ sk, int* __restrict__ cnt) {
  int t = blockIdx.x * 256 + threadIdx.x;
  if (t < NEDGE) cnt[t] = 0;
  if (t == 0) {
#if TF_PARTITIONABLE
    // split_partitionable: key_k = threefry((0,42); threefry_seed(k)=(0,k))
    for (int k = 0; k < 5; ++k) {
      uint32_t o0, o1;
      tf2x32(0u, 42u, 0u, (uint32_t)k, o0, o1);
      sk[2 * k] = o0; sk[2 * k + 1] = o1;
    }
#else
    // split_original: bits = tf over iota(10) split into halves, reshape(5,2)
    uint32_t bits[10];
    for (int l = 0; l < 5; ++l) {
      uint32_t o0, o1;
      tf2x32(0u, 42u, (uint32_t)l, (uint32_t)(l + 5), o0, o1);
      bits[l] = o0; bits[5 + l] = o1;
    }
    for (int k = 0; k < 5; ++k) { sk[2 * k] = bits[2 * k]; sk[2 * k + 1] = bits[2 * k + 1]; }
#endif
  }
}

// Kernel A: extract odd_mask nonzeros into per-column (CSC) lists.
// Coalesced float4 scan of the 64 MB mask; ~14K atomic appends total.
__global__ void prep_odd(const float4* __restrict__ mask4,
                         const float* __restrict__ ow,
                         int* __restrict__ cnt, int* __restrict__ rows,
                         float* __restrict__ wts) {
  int t = blockIdx.x * 256 + threadIdx.x;   // 4,194,304 threads
  float4 m = mask4[t];
  int base = t * 4;
  int r = base >> 12;                        // row e' (4096 divides rows)
  float mv[4] = {m.x, m.y, m.z, m.w};
#pragma unroll
  for (int q = 0; q < 4; ++q) {
    if (mv[q] != 0.0f) {
      int c = (base + q) & 4095;             // column e
      int pos = atomicAdd(&cnt[c], 1);
      if (pos < CAP) {
        rows[c * CAP + pos] = r;
        wts[c * CAP + pos] = ow[base + q];
      }
    }
  }
}

// Kernel B: skip_mask has exactly one nnz per column: record var index + weight.
__global__ void prep_skip(const float4* __restrict__ mask4,
                          const float* __restrict__ lwts,
                          int* __restrict__ var_of, float* __restrict__ lw) {
  int t = blockIdx.x * 256 + threadIdx.x;   // 1,048,576 threads
  float4 m = mask4[t];
  int base = t * 4;
  int r = base >> 12;                        // variable v
  float mv[4] = {m.x, m.y, m.z, m.w};
#pragma unroll
  for (int q = 0; q < 4; ++q) {
    if (mv[q] != 0.0f) {
      int c = (base + q) & 4095;
      var_of[c] = r;
      lw[c] = lwts[base + q];
    }
  }
}

// Main fused kernel: thread owns one edge-column e and BROWS batch rows.
__global__ __launch_bounds__(256) void ldpc_main(
    const float* __restrict__ x, const float* __restrict__ llr,
    const float* __restrict__ dlog, const uint32_t* __restrict__ sk,
    const int* __restrict__ cnt, const int* __restrict__ var_of,
    const float* __restrict__ lw, const int* __restrict__ rows,
    const float* __restrict__ wts, float* __restrict__ out) {
  const int e  = blockIdx.x * 256 + threadIdx.x;  // gridDim.x = 16
  const int b0 = blockIdx.y * BROWS;              // gridDim.y = 512

  uint32_t A[5], B[5];
#pragma unroll
  for (int k = 0; k < 5; ++k) { A[k] = sk[2 * k]; B[k] = sk[2 * k + 1]; }

  int n = cnt[e]; n = n < CAP ? n : CAP;
  const int v = var_of[e];
  const float lwv = lw[e];
  const float kp = 1.0f / (1.0f + __expf(-dlog[e]));  // sigmoid; exact 0.5 at 0

  float s1[BROWS];
#pragma unroll
  for (int bi = 0; bi < BROWS; ++bi) s1[bi] = 0.0f;
  for (int j = 0; j < n; ++j) {
    const int rj = rows[e * CAP + j];
    const float wj = wts[e * CAP + j];
#pragma unroll
    for (int bi = 0; bi < BROWS; ++bi)
      s1[bi] = fmaf(x[(size_t)(b0 + bi) * NEDGE + rj], wj, s1[bi]);
  }

#pragma unroll
  for (int bi = 0; bi < BROWS; ++bi) {
    const float s2 = llr[(size_t)(b0 + bi) * NVAR + v] * lwv;
    const uint32_t i = (uint32_t)(b0 + bi) * (uint32_t)NEDGE + (uint32_t)e;
    float acc = 0.0f;
#pragma unroll
    for (int k = 0; k < 5; ++k) {
      uint32_t o0, o1, bits;
#if TF_PARTITIONABLE
      tf2x32(A[k], B[k], 0u, i, o0, o1);      // count hi=0, lo=i
      bits = o0 ^ o1;
#else
      if (i < (uint32_t)NHALF) { tf2x32(A[k], B[k], i, i + (uint32_t)NHALF, o0, o1); bits = o0; }
      else                     { tf2x32(A[k], B[k], i - (uint32_t)NHALF, i, o0, o1); bits = o1; }
#endif
      const float u = __uint_as_float((bits >> 9) | 0x3f800000u) - 1.0f;
      const float pre = (u < kp) ? (s1[bi] + s2) : s2;   // dropout + skip
      const float oc = fminf(fmaxf(pre, -10.0f), 10.0f); // clip
      const float t = __expf(oc);                        // tanh(oc/2)=(e^oc-1)/(e^oc+1)
      acc += __fdividef(t - 1.0f, t + 1.0f);
    }
    out[(size_t)(b0 + bi) * NEDGE + e] = acc * 0.2f;
  }
}

extern "C" void kernel_launch(void* const* d_in, const int* in_sizes, int n_in,
                              void* d_out, int out_size, void* d_ws, size_t ws_size,
                              hipStream_t stream) {
  const float* x     = (const float*)d_in[0];
  const float* llr   = (const float*)d_in[1];
  const float* ow    = (const float*)d_in[2];
  const float* lwts  = (const float*)d_in[3];
  const float* dlog  = (const float*)d_in[4];
  const float* omask = (const float*)d_in[5];
  const float* smask = (const float*)d_in[6];

  char* ws = (char*)d_ws;
  uint32_t* sk  = (uint32_t*)ws;                      // 64 B (10 words used)
  int*   cnt    = (int*)(ws + 64);                    // 16 KB
  int*   var_of = (int*)(ws + 64 + 16384);            // 16 KB
  float* lw     = (float*)(ws + 64 + 2 * 16384);      // 16 KB
  int*   rows   = (int*)(ws + 64 + 3 * 16384);        // 512 KB
  float* wts    = (float*)(ws + 64 + 3 * 16384 + NEDGE * CAP * 4);  // 512 KB

  prep_zero_keys<<<16, 256, 0, stream>>>(sk, cnt);
  prep_odd<<<(NEDGE * NEDGE / 4) / 256, 256, 0, stream>>>(
      (const float4*)omask, ow, cnt, rows, wts);
  prep_skip<<<(NVAR * NEDGE / 4) / 256, 256, 0, stream>>>(
      (const float4*)smask, lwts, var_of, lw);

  dim3 grid(NEDGE / 256, NBATCH / BROWS);  // 16 x 512
  ldpc_main<<<grid, 256, 0, stream>>>(x, llr, dlog, sk, cnt, var_of, lw,
                                      rows, wts, (float*)d_out);
}

// Round 2
// 442.720 us; speedup vs baseline: 1.4051x; 1.4051x over previous
//
#include <hip/hip_runtime.h>
#include <hip/hip_bf16.h>
#include <stdint.h>

// LDPC BayesianOddLayer — R2.
// R1 passed (partitionable threefry confirmed, absmax 3.9e-3) at 450 us main
// kernel, FETCH 1.24 GB (ideal ~90 MB) -> scattered x-gather overfetch.
// R2: LDS-stage x rows (block owns 4 batch rows x all 4096 edges; x read once,
// gathers hit LDS), and collapse 5 tanh/exp per element to 2 (pre only takes
// two values: s2 or s1+s2; ensemble = weighted count of kept members).

#define NEDGE 4096
#define NVAR  1024
#define NBATCH 4096
#define CAP   32      // max nnz per odd-mask column
#define BROWS 4       // batch rows per block (LDS = BROWS*16KB = 64KB)

__device__ __forceinline__ uint32_t rotl32(uint32_t x, int d) {
  return (x << d) | (x >> (32 - d));
}

// JAX threefry2x32, 20 rounds.
__device__ __forceinline__ void tf2x32(uint32_t k0, uint32_t k1,
                                       uint32_t x0, uint32_t x1,
                                       uint32_t& o0, uint32_t& o1) {
  const uint32_t ks2 = k0 ^ k1 ^ 0x1BD11BDAu;
  x0 += k0; x1 += k1;
#define TF_R(r) { x0 += x1; x1 = rotl32(x1, r); x1 ^= x0; }
  TF_R(13) TF_R(15) TF_R(26) TF_R(6)   x0 += k1;  x1 += ks2 + 1u;
  TF_R(17) TF_R(29) TF_R(16) TF_R(24)  x0 += ks2; x1 += k0 + 2u;
  TF_R(13) TF_R(15) TF_R(26) TF_R(6)   x0 += k0;  x1 += k1 + 3u;
  TF_R(17) TF_R(29) TF_R(16) TF_R(24)  x0 += k1;  x1 += ks2 + 4u;
  TF_R(13) TF_R(15) TF_R(26) TF_R(6)   x0 += ks2; x1 += k0 + 5u;
#undef TF_R
  o0 = x0; o1 = x1;
}

// Kernel 0: zero per-column counters; derive 5 ensemble subkeys
// (jax.random.split(key(42), 5), partitionable: key_k = tf((0,42); 0, k)).
__global__ void prep_zero_keys(uint32_t* __restrict__ sk, int* __restrict__ cnt) {
  int t = blockIdx.x * 256 + threadIdx.x;
  if (t < NEDGE) cnt[t] = 0;
  if (t == 0) {
    for (int k = 0; k < 5; ++k) {
      uint32_t o0, o1;
      tf2x32(0u, 42u, 0u, (uint32_t)k, o0, o1);
      sk[2 * k] = o0; sk[2 * k + 1] = o1;
    }
  }
}

// Kernel A: extract odd_mask nonzeros into per-column (CSC) lists,
// packed {row, weight-bits} entries. Coalesced float4 scan of 64 MB mask.
__global__ void prep_odd(const float4* __restrict__ mask4,
                         const float* __restrict__ ow,
                         int* __restrict__ cnt, int2* __restrict__ ent) {
  int t = blockIdx.x * 256 + threadIdx.x;   // 4,194,304 threads
  float4 m = mask4[t];
  int base = t * 4;
  int r = base >> 12;                        // row e'
  float mv[4] = {m.x, m.y, m.z, m.w};
#pragma unroll
  for (int q = 0; q < 4; ++q) {
    if (mv[q] != 0.0f) {
      int c = (base + q) & 4095;             // column e
      int pos = atomicAdd(&cnt[c], 1);
      if (pos < CAP) ent[c * CAP + pos] = make_int2(r, __float_as_int(ow[base + q]));
    }
  }
}

// Kernel B: skip_mask has exactly one nnz per column: var index + weight.
__global__ void prep_skip(const float4* __restrict__ mask4,
                          const float* __restrict__ lwts,
                          int* __restrict__ var_of, float* __restrict__ lw) {
  int t = blockIdx.x * 256 + threadIdx.x;   // 1,048,576 threads
  float4 m = mask4[t];
  int base = t * 4;
  int r = base >> 12;                        // variable v
  float mv[4] = {m.x, m.y, m.z, m.w};
#pragma unroll
  for (int q = 0; q < 4; ++q) {
    if (mv[q] != 0.0f) {
      int c = (base + q) & 4095;
      var_of[c] = r;
      lw[c] = lwts[base + q];
    }
  }
}

__device__ __forceinline__ float tanh_half(float p) {
  // tanh(clip(p,-10,10)/2) = (e^c - 1)/(e^c + 1)
  const float c = fminf(fmaxf(p, -10.0f), 10.0f);
  const float t = __expf(c);
  return __fdividef(t - 1.0f, t + 1.0f);
}

// Main fused kernel: block owns BROWS batch rows x ALL 4096 edges.
// x rows staged in LDS (read from HBM exactly once, coalesced); sparse
// gathers hit LDS. Ensemble loop only counts kept members; 2 tanh per elem.
__global__ __launch_bounds__(256, 2) void ldpc_main(
    const float* __restrict__ x, const float* __restrict__ llr,
    const float* __restrict__ dlog, const uint32_t* __restrict__ sk,
    const int* __restrict__ cnt, const int* __restrict__ var_of,
    const float* __restrict__ lw, const int2* __restrict__ ent,
    float* __restrict__ out) {
  __shared__ float xs[BROWS][NEDGE];   // 64 KB
  const int tid = threadIdx.x;
  const int b0 = blockIdx.x * BROWS;   // grid = 1024

  // Stage x rows: BROWS * 1024 float4, 256 lanes -> coalesced.
  const float4* x4 = (const float4*)x;
#pragma unroll
  for (int r = 0; r < BROWS; ++r) {
#pragma unroll
    for (int it = 0; it < 4; ++it)
      ((float4*)xs[r])[it * 256 + tid] = x4[(size_t)(b0 + r) * (NEDGE / 4) + it * 256 + tid];
  }
  __syncthreads();

  uint32_t A[5], B[5];
#pragma unroll
  for (int k = 0; k < 5; ++k) { A[k] = sk[2 * k]; B[k] = sk[2 * k + 1]; }

  for (int tile = 0; tile < NEDGE / 256; ++tile) {
    const int e = tile * 256 + tid;
    int n = cnt[e]; n = n < CAP ? n : CAP;
    const int v = var_of[e];
    const float lwv = lw[e];
    const float kp = 1.0f / (1.0f + __expf(-dlog[e]));

    float s1[BROWS];
#pragma unroll
    for (int bi = 0; bi < BROWS; ++bi) s1[bi] = 0.0f;
    for (int j = 0; j < n; ++j) {
      const int2 en = ent[e * CAP + j];
      const float w = __int_as_float(en.y);
#pragma unroll
      for (int bi = 0; bi < BROWS; ++bi)
        s1[bi] = fmaf(xs[bi][en.x], w, s1[bi]);
    }

#pragma unroll
    for (int bi = 0; bi < BROWS; ++bi) {
      const float s2 = llr[(size_t)(b0 + bi) * NVAR + v] * lwv;
      const uint32_t i = (uint32_t)(b0 + bi) * (uint32_t)NEDGE + (uint32_t)e;
      int con = 0;
#pragma unroll
      for (int k = 0; k < 5; ++k) {
        uint32_t o0, o1;
        tf2x32(A[k], B[k], 0u, i, o0, o1);
        const uint32_t bits = o0 ^ o1;
        const float u = __uint_as_float((bits >> 9) | 0x3f800000u) - 1.0f;
        con += (u < kp) ? 1 : 0;
      }
      const float ton  = tanh_half(s1[bi] + s2);
      const float toff = tanh_half(s2);
      out[(size_t)(b0 + bi) * NEDGE + e] =
          0.2f * ((float)con * ton + (float)(5 - con) * toff);
    }
  }
}

extern "C" void kernel_launch(void* const* d_in, const int* in_sizes, int n_in,
                              void* d_out, int out_size, void* d_ws, size_t ws_size,
                              hipStream_t stream) {
  const float* x     = (const float*)d_in[0];
  const float* llr   = (const float*)d_in[1];
  const float* ow    = (const float*)d_in[2];
  const float* lwts  = (const float*)d_in[3];
  const float* dlog  = (const float*)d_in[4];
  const float* omask = (const float*)d_in[5];
  const float* smask = (const float*)d_in[6];

  char* ws = (char*)d_ws;
  uint32_t* sk  = (uint32_t*)ws;                      // 64 B
  int*   cnt    = (int*)(ws + 64);                    // 16 KB
  int*   var_of = (int*)(ws + 64 + 16384);            // 16 KB
  float* lw     = (float*)(ws + 64 + 2 * 16384);      // 16 KB
  int2*  ent    = (int2*)(ws + 64 + 3 * 16384);       // 1 MB

  prep_zero_keys<<<16, 256, 0, stream>>>(sk, cnt);
  prep_odd<<<(NEDGE * NEDGE / 4) / 256, 256, 0, stream>>>(
      (const float4*)omask, ow, cnt, ent);
  prep_skip<<<(NVAR * NEDGE / 4) / 256, 256, 0, stream>>>(
      (const float4*)smask, lwts, var_of, lw);

  ldpc_main<<<NBATCH / BROWS, 256, 0, stream>>>(
      x, llr, dlog, sk, cnt, var_of, lw, ent, (float*)d_out);
}